// Round 11
// baseline (450.975 us; speedup 1.0000x reference)
//
#include <hip/hip_runtime.h>
#include <hip/hip_bf16.h>
#include <math.h>

constexpr int NN   = 8192;   // nodes
constexpr int FIN  = 512;    // input features
constexpr int HC   = 256;    // concat hidden = K(2) * H(128)
constexpr int COUT = 16;     // classes
constexpr int MAXD = 128;    // neighbor cap (avg deg ~33, max ~60)

typedef __attribute__((ext_vector_type(8))) short bf16x8;
typedef __attribute__((ext_vector_type(4))) float f32x4;

__device__ __forceinline__ float lrelu(float x) { return x > 0.f ? x : 0.2f * x; }

__device__ __forceinline__ unsigned short f2bf(float f) {  // RNE f32->bf16
  unsigned u = __float_as_uint(f);
  return (unsigned short)((u + 0x7fffu + ((u >> 16) & 1u)) >> 16);
}
__device__ __forceinline__ float bf2f(unsigned short h) {
  unsigned u = ((unsigned)h) << 16;
  return __uint_as_float(u);
}

// ---------------------------------------------------------------------------
// prep: convert_x (blocks 0..4095), convert_w (4096..4607), zero fs/fd
// (4608..4735), zero H (4736..6783) for gemm1m's k-split atomic accumulate.
// ---------------------------------------------------------------------------
__global__ __launch_bounds__(256) void prep_kernel(const float* __restrict__ x,
                                                   const float* __restrict__ W1,
                                                   unsigned short* __restrict__ Xh,
                                                   unsigned short* __restrict__ Xl,
                                                   unsigned short* __restrict__ Wth,
                                                   unsigned short* __restrict__ Wtl,
                                                   float* __restrict__ fs,
                                                   float* __restrict__ fd,
                                                   float* __restrict__ H) {
  int b = blockIdx.x;
  if (b < 4096) {  // x [8192][512] -> split bf16 (4 floats / thread)
    int t = b * 256 + threadIdx.x;
    float4 v = *reinterpret_cast<const float4*>(x + (size_t)t * 4);
    ushort4 hi, lo;
    hi.x = f2bf(v.x); lo.x = f2bf(v.x - bf2f(hi.x));
    hi.y = f2bf(v.y); lo.y = f2bf(v.y - bf2f(hi.y));
    hi.z = f2bf(v.z); lo.z = f2bf(v.z - bf2f(hi.z));
    hi.w = f2bf(v.w); lo.w = f2bf(v.w - bf2f(hi.w));
    *reinterpret_cast<ushort4*>(Xh + (size_t)t * 4) = hi;
    *reinterpret_cast<ushort4*>(Xl + (size_t)t * 4) = lo;
  } else if (b < 4608) {  // W1 [2][512][128] -> transposed-concat split bf16 [n][f]
    int idx = (b - 4096) * 256 + threadIdx.x;  // n*512 + kk
    int n = idx >> 9, kk = idx & 511;
    int k = n >> 7, h = n & 127;
    float v = W1[k * 65536 + kk * 128 + h];
    unsigned short hi = f2bf(v);
    Wth[idx] = hi;
    Wtl[idx] = f2bf(v - bf2f(hi));
  } else if (b < 4736) {  // zero fs/fd for gemm1m's atomic f-epilogue
    int z = (b - 4608) * 256 + threadIdx.x;  // 0..32767
    if (z < 2 * NN) fs[z] = 0.f;
    else fd[z - 2 * NN] = 0.f;
  } else {  // zero H (2M floats) for gemm1m's k-split atomic accumulate
    int z = (b - 4736) * 256 + threadIdx.x;  // 0..524287, 4 floats each
    *reinterpret_cast<float4*>(H + (size_t)z * 4) = make_float4(0.f, 0.f, 0.f, 0.f);
  }
}

// ---------------------------------------------------------------------------
// H[8192][256] += X @ Wc via split-bf16 MFMA (Ah*Bh + Ah*Bl + Al*Bh).
// K-SPLIT x2 (blockIdx.z): 512 blocks = 2 blocks/CU = 2 waves/SIMD, doubling
// latency-hiding occupancy vs the 256-block variant (modeled ~40-55us,
// latency-bound at 1 wave/SIMD). Partial sums accumulate into zeroed H via
// fp32 atomicAdd. Fused f-epilogue is LINEAR in H, so per-split partial
// contributions atomically summed into fs/fd remain exact.
// ---------------------------------------------------------------------------
__global__ __launch_bounds__(256) void gemm1m(const unsigned short* __restrict__ Xh,
                                              const unsigned short* __restrict__ Xl,
                                              const unsigned short* __restrict__ Bh,
                                              const unsigned short* __restrict__ Bl,
                                              const float* __restrict__ a1s,
                                              const float* __restrict__ a1d,
                                              float* __restrict__ Hout,
                                              float* __restrict__ fs,
                                              float* __restrict__ fd) {
  int wave = threadIdx.x >> 6, lane = threadIdx.x & 63;
  int rowBase = blockIdx.x * 128 + wave * 32;
  int colBase = blockIdx.y * 64;
  int kOff = blockIdx.z * (FIN / 2);
  int frow = lane & 15;            // A-row / B-col within fragment
  int kchunk = (lane >> 4) * 8;    // k sub-chunk within the 32-wide step
  f32x4 acc[2][4] = {};
#pragma unroll 2
  for (int k0 = kOff; k0 < kOff + FIN / 2; k0 += 32) {
    bf16x8 ah[2], al[2], bh[4], bl[4];
#pragma unroll
    for (int r = 0; r < 2; ++r) {
      size_t off = (size_t)(rowBase + r * 16 + frow) * FIN + k0 + kchunk;
      ah[r] = *reinterpret_cast<const bf16x8*>(Xh + off);
      al[r] = *reinterpret_cast<const bf16x8*>(Xl + off);
    }
#pragma unroll
    for (int c = 0; c < 4; ++c) {
      size_t off = (size_t)(colBase + c * 16 + frow) * FIN + k0 + kchunk;
      bh[c] = *reinterpret_cast<const bf16x8*>(Bh + off);
      bl[c] = *reinterpret_cast<const bf16x8*>(Bl + off);
    }
#pragma unroll
    for (int r = 0; r < 2; ++r)
#pragma unroll
      for (int c = 0; c < 4; ++c) {
        acc[r][c] = __builtin_amdgcn_mfma_f32_16x16x32_bf16(ah[r], bh[c], acc[r][c], 0, 0, 0);
        acc[r][c] = __builtin_amdgcn_mfma_f32_16x16x32_bf16(ah[r], bl[c], acc[r][c], 0, 0, 0);
        acc[r][c] = __builtin_amdgcn_mfma_f32_16x16x32_bf16(al[r], bh[c], acc[r][c], 0, 0, 0);
      }
  }
  // D fragment: col = lane&15, row = (lane>>4)*4 + reg   [m89-verified]
  int dcol = lane & 15, drow4 = (lane >> 4) * 4;
#pragma unroll
  for (int r = 0; r < 2; ++r)
#pragma unroll
    for (int c = 0; c < 4; ++c)
#pragma unroll
      for (int q = 0; q < 4; ++q)
        atomicAdd(Hout + (size_t)(rowBase + r * 16 + drow4 + q) * HC + colBase + c * 16 + dcol,
                  acc[r][c][q]);
  // fused f_src/f_dst partial reduction (cols colBase..colBase+63, one head;
  // linear in H so each k-split contributes its share exactly)
  int khead = colBase >> 7;
  float as[4], ad[4];
#pragma unroll
  for (int c = 0; c < 4; ++c) {
    as[c] = a1s[colBase + c * 16 + dcol];
    ad[c] = a1d[colBase + c * 16 + dcol];
  }
#pragma unroll
  for (int r = 0; r < 2; ++r)
#pragma unroll
    for (int q = 0; q < 4; ++q) {
      float s = 0.f, d = 0.f;
#pragma unroll
      for (int c = 0; c < 4; ++c) {
        float v = acc[r][c][q];
        s += v * as[c];
        d += v * ad[c];
      }
#pragma unroll
      for (int off = 8; off > 0; off >>= 1) {
        s += __shfl_xor(s, off, 16);
        d += __shfl_xor(d, off, 16);
      }
      if ((lane & 15) == 0) {
        int row = rowBase + r * 16 + drow4 + q;
        atomicAdd(fs + khead * NN + row, s);
        atomicAdd(fd + khead * NN + row, d);
      }
    }
}

// ---------------------------------------------------------------------------
// Layer-1 sparse attention FUSED with adjacency scan (round-6 structure,
// gemm2 NOT fused — measured regression). One block per row i.
// ---------------------------------------------------------------------------
__global__ __launch_bounds__(256) void attn1_kernel(const void* __restrict__ adj,
                                                    int* __restrict__ nbr,
                                                    int* __restrict__ cnt,
                                                    const float* __restrict__ H,
                                                    const float* __restrict__ fs,
                                                    const float* __restrict__ fd,
                                                    float* __restrict__ H1) {
  __shared__ float att[2][MAXD];
  __shared__ int jidx[MAXD];
  __shared__ int scnt;
  __shared__ int sflag;
  int i = blockIdx.x;
  int t = threadIdx.x;
  if (t == 0) scnt = 0;
  if (t < 64) {
    size_t idx = (size_t)(t * 32) * (size_t)(NN + 1);
    int v = ((const int*)adj)[idx];
    bool four = (v == 1) || (v == 0x3f800000);
    unsigned long long b = __ballot(four);
    if (t == 0) sflag = (b == ~0ull) ? 1 : 0;
  }
  __syncthreads();
  if (sflag) {  // 4-byte elements (int32 or fp32: nonzero bits == edge)
    const int4* row = reinterpret_cast<const int4*>((const int*)adj + (size_t)i * NN);
#pragma unroll
    for (int rep = 0; rep < 8; ++rep) {
      int vi = rep * 256 + t;
      int4 v = row[vi];
      int base = vi * 4;
      if (v.x) { int p = atomicAdd(&scnt, 1); if (p < MAXD) jidx[p] = base; }
      if (v.y) { int p = atomicAdd(&scnt, 1); if (p < MAXD) jidx[p] = base + 1; }
      if (v.z) { int p = atomicAdd(&scnt, 1); if (p < MAXD) jidx[p] = base + 2; }
      if (v.w) { int p = atomicAdd(&scnt, 1); if (p < MAXD) jidx[p] = base + 3; }
    }
  } else {  // 1-byte elements
    const uint4* row = reinterpret_cast<const uint4*>((const unsigned char*)adj + (size_t)i * NN);
#pragma unroll
    for (int rep = 0; rep < 2; ++rep) {
      int vi = rep * 256 + t;
      uint4 v = row[vi];
      int base = vi * 16;
      unsigned w[4] = {v.x, v.y, v.z, v.w};
#pragma unroll
      for (int q = 0; q < 4; ++q)
#pragma unroll
        for (int bb = 0; bb < 4; ++bb)
          if ((w[q] >> (8 * bb)) & 0xffu) {
            int p = atomicAdd(&scnt, 1);
            if (p < MAXD) jidx[p] = base + q * 4 + bb;
          }
    }
  }
  __syncthreads();
  int deg = scnt < MAXD ? scnt : MAXD;
  if (t == 0) cnt[i] = deg;
  if (t < deg) {
    int j = jidx[t];
    nbr[(size_t)i * MAXD + t] = j;       // for attn2
    att[0][t] = lrelu(fs[i] + fd[j]);
    att[1][t] = lrelu(fs[NN + i] + fd[NN + j]);
  }
  __syncthreads();
  int wave = t >> 6, lane = t & 63;
  if (wave < 2) {
    int k = wave;
    float e0 = (lane < deg) ? att[k][lane] : -INFINITY;
    float e1 = (lane + 64 < deg) ? att[k][lane + 64] : -INFINITY;
    float m = fmaxf(e0, e1);
#pragma unroll
    for (int off = 32; off > 0; off >>= 1) m = fmaxf(m, __shfl_xor(m, off));
    float p0 = (lane < deg) ? expf(e0 - m) : 0.f;
    float p1 = (lane + 64 < deg) ? expf(e1 - m) : 0.f;
    float s = p0 + p1;
#pragma unroll
    for (int off = 32; off > 0; off >>= 1) s += __shfl_xor(s, off);
    float inv = 1.f / s;   // s > 0 guaranteed by self-loop
    if (lane < deg) att[k][lane] = p0 * inv;
    if (lane + 64 < deg) att[k][lane + 64] = p1 * inv;
  }
  __syncthreads();
  int k = t >> 7;
  float acc = 0.f;
  int q = 0;
  for (; q + 4 <= deg; q += 4) {
    float a0 = att[k][q], a1 = att[k][q + 1], a2 = att[k][q + 2], a3 = att[k][q + 3];
    int j0 = jidx[q], j1 = jidx[q + 1], j2 = jidx[q + 2], j3 = jidx[q + 3];
    float g0 = H[(size_t)j0 * HC + t];
    float g1 = H[(size_t)j1 * HC + t];
    float g2 = H[(size_t)j2 * HC + t];
    float g3 = H[(size_t)j3 * HC + t];
    acc += a0 * g0 + a1 * g1 + a2 * g2 + a3 * g3;
  }
  for (; q < deg; ++q) acc += att[k][q] * H[(size_t)jidx[q] * HC + t];
  H1[(size_t)i * HC + t] = fmaxf(acc, 0.f);  // relu(elu(z)) == relu(z)
}

// ---------------------------------------------------------------------------
// H2[8192][16] = H1[8192][256] @ W2[256][16], fused f2_src/f2_dst reduction.
// ---------------------------------------------------------------------------
__global__ __launch_bounds__(256) void gemm2_kernel(const float* __restrict__ H1,
                                                    const float* __restrict__ W2,
                                                    const float* __restrict__ a2s,
                                                    const float* __restrict__ a2d,
                                                    float* __restrict__ H2,
                                                    float* __restrict__ f2s,
                                                    float* __restrict__ f2d) {
  __shared__ float Ws[HC * COUT];
  int tid = threadIdx.x;
#pragma unroll
  for (int r = 0; r < 16; ++r) Ws[r * 256 + tid] = W2[r * 256 + tid];
  __syncthreads();
  int rg = tid >> 4, c = tid & 15;
  int n = blockIdx.x * 16 + rg;
  const float* h1r = H1 + (size_t)n * HC;
  float acc = 0.f;
#pragma unroll 8
  for (int kk = 0; kk < HC; ++kk) acc += h1r[kk] * Ws[kk * COUT + c];
  H2[(size_t)n * COUT + c] = acc;
  float s = acc * a2s[c];
  float d = acc * a2d[c];
#pragma unroll
  for (int off = 8; off > 0; off >>= 1) {
    s += __shfl_xor(s, off, 16);
    d += __shfl_xor(d, off, 16);
  }
  if (c == 0) { f2s[n] = s; f2d[n] = d; }
}

// ---------------------------------------------------------------------------
// Layer-2 sparse attention; K=1 head so mean == identity. One wave per row.
// ---------------------------------------------------------------------------
__global__ __launch_bounds__(64) void attn2_kernel(const int* __restrict__ nbr,
                                                   const int* __restrict__ cnt,
                                                   const float* __restrict__ H2,
                                                   const float* __restrict__ fs,
                                                   const float* __restrict__ fd,
                                                   float* __restrict__ out) {
  __shared__ float att[MAXD];
  __shared__ int jj[MAXD];
  int i = blockIdx.x;
  int lane = threadIdx.x;
  int deg = cnt[i];
  float fsi = fs[i];
  int j0 = (lane < deg) ? nbr[(size_t)i * MAXD + lane] : 0;
  int j1 = (lane + 64 < deg) ? nbr[(size_t)i * MAXD + lane + 64] : 0;
  float e0 = (lane < deg) ? lrelu(fsi + fd[j0]) : -INFINITY;
  float e1 = (lane + 64 < deg) ? lrelu(fsi + fd[j1]) : -INFINITY;
  float m = fmaxf(e0, e1);
#pragma unroll
  for (int off = 32; off > 0; off >>= 1) m = fmaxf(m, __shfl_xor(m, off));
  float p0 = (lane < deg) ? expf(e0 - m) : 0.f;
  float p1 = (lane + 64 < deg) ? expf(e1 - m) : 0.f;
  float s = p0 + p1;
#pragma unroll
  for (int off = 32; off > 0; off >>= 1) s += __shfl_xor(s, off);
  float inv = 1.f / s;
  att[lane] = p0 * inv;
  att[lane + 64] = p1 * inv;
  jj[lane] = j0;
  jj[lane + 64] = j1;
  __syncthreads();
  if (lane < COUT) {
    float acc = 0.f;
    for (int q = 0; q < deg; ++q) acc += att[q] * H2[(size_t)jj[q] * COUT + lane];
    out[(size_t)i * COUT + lane] = acc;
  }
}

// ---------------------------------------------------------------------------
extern "C" void kernel_launch(void* const* d_in, const int* in_sizes, int n_in,
                              void* d_out, int out_size, void* d_ws, size_t ws_size,
                              hipStream_t stream) {
  const float* x   = (const float*)d_in[0];
  const void*  adj = d_in[1];
  const float* W1  = (const float*)d_in[2];
  const float* a1s = (const float*)d_in[3];
  const float* a1d = (const float*)d_in[4];
  const float* W2  = (const float*)d_in[5];
  const float* a2s = (const float*)d_in[6];
  const float* a2d = (const float*)d_in[7];
  float* out = (float*)d_out;

  char* ws = (char*)d_ws;
  size_t off = 0;
  auto alloc = [&](size_t bytes) -> void* {
    void* p = ws + off;
    off = (off + bytes + 255) & ~(size_t)255;
    return p;
  };
  int*            nbr  = (int*)           alloc((size_t)NN * MAXD * 4);
  int*            cnt  = (int*)           alloc((size_t)NN * 4);
  unsigned short* Xh   = (unsigned short*)alloc((size_t)NN * FIN * 2);
  unsigned short* Xl   = (unsigned short*)alloc((size_t)NN * FIN * 2);
  unsigned short* Wth  = (unsigned short*)alloc((size_t)HC * FIN * 2);
  unsigned short* Wtl  = (unsigned short*)alloc((size_t)HC * FIN * 2);
  float*          H    = (float*)         alloc((size_t)NN * HC * 4);
  float*          fs   = (float*)         alloc((size_t)2 * NN * 4);
  float*          fd   = (float*)         alloc((size_t)2 * NN * 4);
  float*          H1   = (float*)         alloc((size_t)NN * HC * 4);
  float*          H2   = (float*)         alloc((size_t)NN * COUT * 4);
  float*          f2s  = (float*)         alloc((size_t)NN * 4);
  float*          f2d  = (float*)         alloc((size_t)NN * 4);

  hipLaunchKernelGGL(prep_kernel, dim3(6784), dim3(256), 0, stream,
                     x, W1, Xh, Xl, Wth, Wtl, fs, fd, H);
  hipLaunchKernelGGL(gemm1m, dim3(NN / 128, HC / 64, 2), dim3(256), 0, stream,
                     Xh, Xl, Wth, Wtl, a1s, a1d, H, fs, fd);
  hipLaunchKernelGGL(attn1_kernel, dim3(NN), dim3(256), 0, stream,
                     adj, nbr, cnt, H, fs, fd, H1);
  hipLaunchKernelGGL(gemm2_kernel, dim3(NN / 16), dim3(256), 0, stream,
                     H1, W2, a2s, a2d, H2, f2s, f2d);
  hipLaunchKernelGGL(attn2_kernel, dim3(NN), dim3(64), 0, stream,
                     nbr, cnt, H2, f2s, f2d, out);
}

// Round 13
// 438.100 us; speedup vs baseline: 1.0294x; 1.0294x over previous
//
#include <hip/hip_runtime.h>
#include <hip/hip_bf16.h>
#include <hip/hip_fp16.h>
#include <math.h>

constexpr int NN   = 8192;   // nodes
constexpr int FIN  = 512;    // input features
constexpr int HC   = 256;    // concat hidden = K(2) * H(128)
constexpr int COUT = 16;     // classes
constexpr int MAXD = 128;    // neighbor cap (avg deg ~33, max ~60)

typedef __attribute__((ext_vector_type(8))) short bf16x8;
typedef __attribute__((ext_vector_type(4))) float f32x4;

__device__ __forceinline__ float lrelu(float x) { return x > 0.f ? x : 0.2f * x; }

__device__ __forceinline__ unsigned short f2bf(float f) {  // RNE f32->bf16
  unsigned u = __float_as_uint(f);
  return (unsigned short)((u + 0x7fffu + ((u >> 16) & 1u)) >> 16);
}
__device__ __forceinline__ float bf2f(unsigned short h) {
  unsigned u = ((unsigned)h) << 16;
  return __uint_as_float(u);
}

// ---------------------------------------------------------------------------
// prep: convert_x (blocks 0..4095), convert_w (4096..4607), zero fs/fd
// (4608..4735).  (R6 structure — no H zeroing, gemm1m uses plain stores.)
// ---------------------------------------------------------------------------
__global__ __launch_bounds__(256) void prep_kernel(const float* __restrict__ x,
                                                   const float* __restrict__ W1,
                                                   unsigned short* __restrict__ Xh,
                                                   unsigned short* __restrict__ Xl,
                                                   unsigned short* __restrict__ Wth,
                                                   unsigned short* __restrict__ Wtl,
                                                   float* __restrict__ fs,
                                                   float* __restrict__ fd) {
  int b = blockIdx.x;
  if (b < 4096) {  // x [8192][512] -> split bf16 (4 floats / thread)
    int t = b * 256 + threadIdx.x;
    float4 v = *reinterpret_cast<const float4*>(x + (size_t)t * 4);
    ushort4 hi, lo;
    hi.x = f2bf(v.x); lo.x = f2bf(v.x - bf2f(hi.x));
    hi.y = f2bf(v.y); lo.y = f2bf(v.y - bf2f(hi.y));
    hi.z = f2bf(v.z); lo.z = f2bf(v.z - bf2f(hi.z));
    hi.w = f2bf(v.w); lo.w = f2bf(v.w - bf2f(hi.w));
    *reinterpret_cast<ushort4*>(Xh + (size_t)t * 4) = hi;
    *reinterpret_cast<ushort4*>(Xl + (size_t)t * 4) = lo;
  } else if (b < 4608) {  // W1 [2][512][128] -> transposed-concat split bf16 [n][f]
    int idx = (b - 4096) * 256 + threadIdx.x;  // n*512 + kk
    int n = idx >> 9, kk = idx & 511;
    int k = n >> 7, h = n & 127;
    float v = W1[k * 65536 + kk * 128 + h];
    unsigned short hi = f2bf(v);
    Wth[idx] = hi;
    Wtl[idx] = f2bf(v - bf2f(hi));
  } else {  // zero fs/fd for gemm1m's atomic f-epilogue
    int z = (b - 4608) * 256 + threadIdx.x;  // 0..32767
    if (z < 2 * NN) fs[z] = 0.f;
    else fd[z - 2 * NN] = 0.f;
  }
}

// ---------------------------------------------------------------------------
// H[8192][256] = X @ Wc via split-bf16 MFMA (Ah*Bh + Ah*Bl + Al*Bh).
// R6 structure (no k-split, plain stores — k-split+atomics measured +12us
// regression, R11). CHANGE vs R6: H stored as FP16 (2^-11 rel error, |H|<~5)
// -> halves attn1's 270MB gather and this kernel's H write. fs/fd epilogue
// still reduces the exact fp32 accumulators.
// ---------------------------------------------------------------------------
__global__ __launch_bounds__(256) void gemm1m(const unsigned short* __restrict__ Xh,
                                              const unsigned short* __restrict__ Xl,
                                              const unsigned short* __restrict__ Bh,
                                              const unsigned short* __restrict__ Bl,
                                              const float* __restrict__ a1s,
                                              const float* __restrict__ a1d,
                                              __half* __restrict__ Hout,
                                              float* __restrict__ fs,
                                              float* __restrict__ fd) {
  int wave = threadIdx.x >> 6, lane = threadIdx.x & 63;
  int rowBase = blockIdx.x * 128 + wave * 32;
  int colBase = blockIdx.y * 64;
  int frow = lane & 15;            // A-row / B-col within fragment
  int kchunk = (lane >> 4) * 8;    // k sub-chunk within the 32-wide step
  f32x4 acc[2][4] = {};
  for (int k0 = 0; k0 < FIN; k0 += 32) {
    bf16x8 ah[2], al[2], bh[4], bl[4];
#pragma unroll
    for (int r = 0; r < 2; ++r) {
      size_t off = (size_t)(rowBase + r * 16 + frow) * FIN + k0 + kchunk;
      ah[r] = *reinterpret_cast<const bf16x8*>(Xh + off);
      al[r] = *reinterpret_cast<const bf16x8*>(Xl + off);
    }
#pragma unroll
    for (int c = 0; c < 4; ++c) {
      size_t off = (size_t)(colBase + c * 16 + frow) * FIN + k0 + kchunk;
      bh[c] = *reinterpret_cast<const bf16x8*>(Bh + off);
      bl[c] = *reinterpret_cast<const bf16x8*>(Bl + off);
    }
#pragma unroll
    for (int r = 0; r < 2; ++r)
#pragma unroll
      for (int c = 0; c < 4; ++c) {
        acc[r][c] = __builtin_amdgcn_mfma_f32_16x16x32_bf16(ah[r], bh[c], acc[r][c], 0, 0, 0);
        acc[r][c] = __builtin_amdgcn_mfma_f32_16x16x32_bf16(ah[r], bl[c], acc[r][c], 0, 0, 0);
        acc[r][c] = __builtin_amdgcn_mfma_f32_16x16x32_bf16(al[r], bh[c], acc[r][c], 0, 0, 0);
      }
  }
  // D fragment: col = lane&15, row = (lane>>4)*4 + reg   [m89-verified]
  int dcol = lane & 15, drow4 = (lane >> 4) * 4;
#pragma unroll
  for (int r = 0; r < 2; ++r)
#pragma unroll
    for (int c = 0; c < 4; ++c)
#pragma unroll
      for (int q = 0; q < 4; ++q)
        Hout[(size_t)(rowBase + r * 16 + drow4 + q) * HC + colBase + c * 16 + dcol] =
            __float2half(acc[r][c][q]);
  // fused f_src/f_dst partial reduction (cols colBase..colBase+63, one head;
  // exact fp32 accumulators — H's fp16 rounding does not touch fs/fd)
  int khead = colBase >> 7;
  float as[4], ad[4];
#pragma unroll
  for (int c = 0; c < 4; ++c) {
    as[c] = a1s[colBase + c * 16 + dcol];
    ad[c] = a1d[colBase + c * 16 + dcol];
  }
#pragma unroll
  for (int r = 0; r < 2; ++r)
#pragma unroll
    for (int q = 0; q < 4; ++q) {
      float s = 0.f, d = 0.f;
#pragma unroll
      for (int c = 0; c < 4; ++c) {
        float v = acc[r][c][q];
        s += v * as[c];
        d += v * ad[c];
      }
#pragma unroll
      for (int off = 8; off > 0; off >>= 1) {
        s += __shfl_xor(s, off, 16);
        d += __shfl_xor(d, off, 16);
      }
      if ((lane & 15) == 0) {
        int row = rowBase + r * 16 + drow4 + q;
        atomicAdd(fs + khead * NN + row, s);
        atomicAdd(fd + khead * NN + row, d);
      }
    }
}

// ---------------------------------------------------------------------------
// Layer-1 sparse attention FUSED with adjacency scan (R6 structure).
// One block per row i. PV gather now reads FP16 H (half the bytes).
// ---------------------------------------------------------------------------
__global__ __launch_bounds__(256) void attn1_kernel(const void* __restrict__ adj,
                                                    int* __restrict__ nbr,
                                                    int* __restrict__ cnt,
                                                    const __half* __restrict__ H,
                                                    const float* __restrict__ fs,
                                                    const float* __restrict__ fd,
                                                    float* __restrict__ H1) {
  __shared__ float att[2][MAXD];
  __shared__ int jidx[MAXD];
  __shared__ int scnt;
  __shared__ int sflag;
  int i = blockIdx.x;
  int t = threadIdx.x;
  if (t == 0) scnt = 0;
  if (t < 64) {
    size_t idx = (size_t)(t * 32) * (size_t)(NN + 1);
    int v = ((const int*)adj)[idx];
    bool four = (v == 1) || (v == 0x3f800000);
    unsigned long long b = __ballot(four);
    if (t == 0) sflag = (b == ~0ull) ? 1 : 0;
  }
  __syncthreads();
  if (sflag) {  // 4-byte elements (int32 or fp32: nonzero bits == edge)
    const int4* row = reinterpret_cast<const int4*>((const int*)adj + (size_t)i * NN);
#pragma unroll
    for (int rep = 0; rep < 8; ++rep) {
      int vi = rep * 256 + t;
      int4 v = row[vi];
      int base = vi * 4;
      if (v.x) { int p = atomicAdd(&scnt, 1); if (p < MAXD) jidx[p] = base; }
      if (v.y) { int p = atomicAdd(&scnt, 1); if (p < MAXD) jidx[p] = base + 1; }
      if (v.z) { int p = atomicAdd(&scnt, 1); if (p < MAXD) jidx[p] = base + 2; }
      if (v.w) { int p = atomicAdd(&scnt, 1); if (p < MAXD) jidx[p] = base + 3; }
    }
  } else {  // 1-byte elements
    const uint4* row = reinterpret_cast<const uint4*>((const unsigned char*)adj + (size_t)i * NN);
#pragma unroll
    for (int rep = 0; rep < 2; ++rep) {
      int vi = rep * 256 + t;
      uint4 v = row[vi];
      int base = vi * 16;
      unsigned w[4] = {v.x, v.y, v.z, v.w};
#pragma unroll
      for (int q = 0; q < 4; ++q)
#pragma unroll
        for (int bb = 0; bb < 4; ++bb)
          if ((w[q] >> (8 * bb)) & 0xffu) {
            int p = atomicAdd(&scnt, 1);
            if (p < MAXD) jidx[p] = base + q * 4 + bb;
          }
    }
  }
  __syncthreads();
  int deg = scnt < MAXD ? scnt : MAXD;
  if (t == 0) cnt[i] = deg;
  if (t < deg) {
    int j = jidx[t];
    nbr[(size_t)i * MAXD + t] = j;       // for attn2
    att[0][t] = lrelu(fs[i] + fd[j]);
    att[1][t] = lrelu(fs[NN + i] + fd[NN + j]);
  }
  __syncthreads();
  int wave = t >> 6, lane = t & 63;
  if (wave < 2) {
    int k = wave;
    float e0 = (lane < deg) ? att[k][lane] : -INFINITY;
    float e1 = (lane + 64 < deg) ? att[k][lane + 64] : -INFINITY;
    float m = fmaxf(e0, e1);
#pragma unroll
    for (int off = 32; off > 0; off >>= 1) m = fmaxf(m, __shfl_xor(m, off));
    float p0 = (lane < deg) ? expf(e0 - m) : 0.f;
    float p1 = (lane + 64 < deg) ? expf(e1 - m) : 0.f;
    float s = p0 + p1;
#pragma unroll
    for (int off = 32; off > 0; off >>= 1) s += __shfl_xor(s, off);
    float inv = 1.f / s;   // s > 0 guaranteed by self-loop
    if (lane < deg) att[k][lane] = p0 * inv;
    if (lane + 64 < deg) att[k][lane + 64] = p1 * inv;
  }
  __syncthreads();
  int k = t >> 7;
  float acc = 0.f;
  int q = 0;
  for (; q + 4 <= deg; q += 4) {
    float a0 = att[k][q], a1 = att[k][q + 1], a2 = att[k][q + 2], a3 = att[k][q + 3];
    int j0 = jidx[q], j1 = jidx[q + 1], j2 = jidx[q + 2], j3 = jidx[q + 3];
    float g0 = __half2float(H[(size_t)j0 * HC + t]);
    float g1 = __half2float(H[(size_t)j1 * HC + t]);
    float g2 = __half2float(H[(size_t)j2 * HC + t]);
    float g3 = __half2float(H[(size_t)j3 * HC + t]);
    acc += a0 * g0 + a1 * g1 + a2 * g2 + a3 * g3;
  }
  for (; q < deg; ++q) acc += att[k][q] * __half2float(H[(size_t)jidx[q] * HC + t]);
  H1[(size_t)i * HC + t] = fmaxf(acc, 0.f);  // relu(elu(z)) == relu(z)
}

// ---------------------------------------------------------------------------
// H2[8192][16] = H1[8192][256] @ W2[256][16], fused f2_src/f2_dst reduction.
// ---------------------------------------------------------------------------
__global__ __launch_bounds__(256) void gemm2_kernel(const float* __restrict__ H1,
                                                    const float* __restrict__ W2,
                                                    const float* __restrict__ a2s,
                                                    const float* __restrict__ a2d,
                                                    float* __restrict__ H2,
                                                    float* __restrict__ f2s,
                                                    float* __restrict__ f2d) {
  __shared__ float Ws[HC * COUT];
  int tid = threadIdx.x;
#pragma unroll
  for (int r = 0; r < 16; ++r) Ws[r * 256 + tid] = W2[r * 256 + tid];
  __syncthreads();
  int rg = tid >> 4, c = tid & 15;
  int n = blockIdx.x * 16 + rg;
  const float* h1r = H1 + (size_t)n * HC;
  float acc = 0.f;
#pragma unroll 8
  for (int kk = 0; kk < HC; ++kk) acc += h1r[kk] * Ws[kk * COUT + c];
  H2[(size_t)n * COUT + c] = acc;
  float s = acc * a2s[c];
  float d = acc * a2d[c];
#pragma unroll
  for (int off = 8; off > 0; off >>= 1) {
    s += __shfl_xor(s, off, 16);
    d += __shfl_xor(d, off, 16);
  }
  if (c == 0) { f2s[n] = s; f2d[n] = d; }
}

// ---------------------------------------------------------------------------
// Layer-2 sparse attention; K=1 head so mean == identity. One wave per row.
// ---------------------------------------------------------------------------
__global__ __launch_bounds__(64) void attn2_kernel(const int* __restrict__ nbr,
                                                   const int* __restrict__ cnt,
                                                   const float* __restrict__ H2,
                                                   const float* __restrict__ fs,
                                                   const float* __restrict__ fd,
                                                   float* __restrict__ out) {
  __shared__ float att[MAXD];
  __shared__ int jj[MAXD];
  int i = blockIdx.x;
  int lane = threadIdx.x;
  int deg = cnt[i];
  float fsi = fs[i];
  int j0 = (lane < deg) ? nbr[(size_t)i * MAXD + lane] : 0;
  int j1 = (lane + 64 < deg) ? nbr[(size_t)i * MAXD + lane + 64] : 0;
  float e0 = (lane < deg) ? lrelu(fsi + fd[j0]) : -INFINITY;
  float e1 = (lane + 64 < deg) ? lrelu(fsi + fd[j1]) : -INFINITY;
  float m = fmaxf(e0, e1);
#pragma unroll
  for (int off = 32; off > 0; off >>= 1) m = fmaxf(m, __shfl_xor(m, off));
  float p0 = (lane < deg) ? expf(e0 - m) : 0.f;
  float p1 = (lane + 64 < deg) ? expf(e1 - m) : 0.f;
  float s = p0 + p1;
#pragma unroll
  for (int off = 32; off > 0; off >>= 1) s += __shfl_xor(s, off);
  float inv = 1.f / s;
  att[lane] = p0 * inv;
  att[lane + 64] = p1 * inv;
  jj[lane] = j0;
  jj[lane + 64] = j1;
  __syncthreads();
  if (lane < COUT) {
    float acc = 0.f;
    for (int q = 0; q < deg; ++q) acc += att[q] * H2[(size_t)jj[q] * COUT + lane];
    out[(size_t)i * COUT + lane] = acc;
  }
}

// ---------------------------------------------------------------------------
extern "C" void kernel_launch(void* const* d_in, const int* in_sizes, int n_in,
                              void* d_out, int out_size, void* d_ws, size_t ws_size,
                              hipStream_t stream) {
  const float* x   = (const float*)d_in[0];
  const void*  adj = d_in[1];
  const float* W1  = (const float*)d_in[2];
  const float* a1s = (const float*)d_in[3];
  const float* a1d = (const float*)d_in[4];
  const float* W2  = (const float*)d_in[5];
  const float* a2s = (const float*)d_in[6];
  const float* a2d = (const float*)d_in[7];
  float* out = (float*)d_out;

  char* ws = (char*)d_ws;
  size_t off = 0;
  auto alloc = [&](size_t bytes) -> void* {
    void* p = ws + off;
    off = (off + bytes + 255) & ~(size_t)255;
    return p;
  };
  int*            nbr  = (int*)           alloc((size_t)NN * MAXD * 4);
  int*            cnt  = (int*)           alloc((size_t)NN * 4);
  unsigned short* Xh   = (unsigned short*)alloc((size_t)NN * FIN * 2);
  unsigned short* Xl   = (unsigned short*)alloc((size_t)NN * FIN * 2);
  unsigned short* Wth  = (unsigned short*)alloc((size_t)HC * FIN * 2);
  unsigned short* Wtl  = (unsigned short*)alloc((size_t)HC * FIN * 2);
  __half*         H    = (__half*)        alloc((size_t)NN * HC * 2);
  float*          fs   = (float*)         alloc((size_t)2 * NN * 4);
  float*          fd   = (float*)         alloc((size_t)2 * NN * 4);
  float*          H1   = (float*)         alloc((size_t)NN * HC * 4);
  float*          H2   = (float*)         alloc((size_t)NN * COUT * 4);
  float*          f2s  = (float*)         alloc((size_t)NN * 4);
  float*          f2d  = (float*)         alloc((size_t)NN * 4);

  hipLaunchKernelGGL(prep_kernel, dim3(4736), dim3(256), 0, stream,
                     x, W1, Xh, Xl, Wth, Wtl, fs, fd);
  hipLaunchKernelGGL(gemm1m, dim3(NN / 128, HC / 64), dim3(256), 0, stream,
                     Xh, Xl, Wth, Wtl, a1s, a1d, H, fs, fd);
  hipLaunchKernelGGL(attn1_kernel, dim3(NN), dim3(256), 0, stream,
                     adj, nbr, cnt, H, fs, fd, H1);
  hipLaunchKernelGGL(gemm2_kernel, dim3(NN / 16), dim3(256), 0, stream,
                     H1, W2, a2s, a2d, H2, f2s, f2d);
  hipLaunchKernelGGL(attn2_kernel, dim3(NN), dim3(64), 0, stream,
                     nbr, cnt, H2, f2s, f2d, out);
}